// Round 20
// baseline (99.081 us; speedup 1.0000x reference)
//
#include <hip/hip_runtime.h>
#include <hip/hip_bf16.h>
#include <stdint.h>

#define B_    8
#define CIN   64
#define COUT  64
#define NPATH 9
#define H_    128
#define W_    128
#define HW    16384
#define PTOT  131072   // B*H*W
#define NBIN  72       // NPATH * B_
#define CHUNK 32       // pixels per chunk
#define NBLK  512      // persistent k_conv blocks (2 per CU)
#define NSCORE 1024    // scoring blocks (128 px each)

typedef float  f32x4   __attribute__((ext_vector_type(4)));
typedef float  f32x16  __attribute__((ext_vector_type(16)));
typedef __bf16 bf16x8  __attribute__((ext_vector_type(8)));
typedef short  short8  __attribute__((ext_vector_type(8)));
typedef unsigned short ushort4v __attribute__((ext_vector_type(4)));

__device__ __forceinline__ short f2bf(float f) {
    __bf16 b = (__bf16)f;
    return __builtin_bit_cast(short, b);
}
__device__ __forceinline__ float bf2f(unsigned short u) {
    unsigned v = ((unsigned)u) << 16;
    return __builtin_bit_cast(float, v);
}
__device__ __forceinline__ float fast_tanh(float a) {
    float e = __builtin_amdgcn_exp2f(a * 2.885390081777927f);
    return 1.0f - 2.0f / (e + 1.0f);
}

// Hot atomic targets padded to one 64B cache line each.
#define GC(arr, i)  ((arr)[(i) * 16])        // gcnt: u32 stride 16
#define SM(arr, i)  ((arr)[(i) * 16])        // sums: f32 stride 16

// ---------------------------------------------------------------- K0:
__global__ void k_zero(f32x4* __restrict__ dst) {
    int i = blockIdx.x * 256 + threadIdx.x;    // 5120 f32x4 = 81920 B
    if (i < 5120) dst[i] = (f32x4)0.0f;
}

// ---------------------------------------------------------------- K1 (fused):
// blocks 0..1023: 128 px/block. x-tile + w1T + w2/b2 in LDS.
//   MLP1 j-stationary; tail: waves 0-1 MLP2 (LDS broadcast weights) /argmax/
//   compaction, waves 2-3 Xb emit.
// blocks 1024..1104: kernels_w -> WbF MFMA-fragment order
__global__ __launch_bounds__(256, 2) void k_pre(
                      const float* __restrict__ x,
                      const float* __restrict__ w1, const float* __restrict__ b1,
                      const float* __restrict__ w2, const float* __restrict__ b2,
                      const float* __restrict__ kw,
                      unsigned* __restrict__ gcnt, unsigned* __restrict__ lists,
                      unsigned short* __restrict__ Xb,
                      unsigned short* __restrict__ WbF) {
    int t = threadIdx.x;
    if (blockIdx.x >= NSCORE) {
        int ob = ((int)blockIdx.x - NSCORE) * 4096 + t * 16;
        #pragma unroll
        for (int j = 0; j < 16; ++j) {
            int o = ob + j;
            int jj   = o & 7;
            int lane = (o >> 3) & 63;
            int f    = (o >> 9) & 3;
            int rest = o >> 11;
            int s    = rest % 18;
            int n    = rest / 18;
            int c    = f * 16 + (lane & 15);
            int kg   = lane >> 4;
            int ci   = ((s & 1) << 5) + (kg << 3) + jj;
            int tap  = s >> 1;
            WbF[o] = (unsigned short)f2bf(kw[((n * 64 + c) * 64 + ci) * 9 + tap]);
        }
        return;
    }
    __shared__ float xt[64 * 128];     // 32 KB  [ch][px]
    __shared__ float ht[32 * 128];     // 16 KB  [j][px]
    __shared__ float w1t[64 * 36];     // 9.2 KB [ch][j]
    __shared__ float w2s[304];         // 288 w2 + 9 b2
    __shared__ unsigned scnt[NBIN];
    __shared__ unsigned sbase[NBIN];

    int px0 = blockIdx.x * 128;
    int b   = blockIdx.x >> 7;         // 128 blocks per batch
    int hw0 = px0 & 16383;
    if (t < NBIN) scnt[t] = 0u;

    // ---- stage x-tile: 8 coalesced f32x4 per thread
    const float* xbp = x + (((size_t)b) << 20) + hw0;
    #pragma unroll
    for (int i = 0; i < 8; ++i) {
        int flat = i * 256 + t;            // f32x4 id 0..2047
        int ch = flat >> 5, ck = flat & 31;
        f32x4 v = *(const f32x4*)(xbp + ch * HW + ck * 4);
        *(f32x4*)(&xt[ch * 128 + ck * 4]) = v;
    }
    // ---- stage w1 transposed + w2 + b2
    #pragma unroll
    for (int i = 0; i < 8; ++i) {
        int flat = i * 256 + t;            // 0..2047
        int j = flat >> 6, ch = flat & 63;
        w1t[ch * 36 + j] = w1[flat];
    }
    for (int i = t; i < 288; i += 256) w2s[i] = w2[i];
    if (t < 9) w2s[288 + t] = b2[t];
    __syncthreads();

    // ---- MLP1: wave wv owns j in [wv*8, wv*8+8); lane l -> px {2l, 2l+1}
    int wv = t >> 6, l = t & 63;
    {
        float acc[8][2];
        #pragma unroll
        for (int jj = 0; jj < 8; ++jj) {
            float bj = b1[wv * 8 + jj];
            acc[jj][0] = bj; acc[jj][1] = bj;
        }
        #pragma unroll 8
        for (int ch = 0; ch < 64; ++ch) {
            f32x4 wa = *(const f32x4*)(&w1t[ch * 36 + wv * 8]);      // broadcast
            f32x4 wb = *(const f32x4*)(&w1t[ch * 36 + wv * 8 + 4]);  // broadcast
            float2 xx = *(const float2*)(&xt[ch * 128 + l * 2]);
            #pragma unroll
            for (int jj = 0; jj < 4; ++jj) {
                acc[jj][0]     += xx.x * wa[jj];
                acc[jj][1]     += xx.y * wa[jj];
                acc[4 + jj][0] += xx.x * wb[jj];
                acc[4 + jj][1] += xx.y * wb[jj];
            }
        }
        #pragma unroll
        for (int jj = 0; jj < 8; ++jj)
            *(float2*)(&ht[(wv * 8 + jj) * 128 + l * 2]) =
                make_float2(acc[jj][0], acc[jj][1]);
    }
    __syncthreads();

    // ---- tail: waves 0-1 = MLP2/argmax (LDS weights); waves 2-3 = Xb emit
    int bin = 0; unsigned rank = 0;
    if (t < 128) {
        int px = t;
        float h[32];
        #pragma unroll
        for (int j = 0; j < 32; ++j) h[j] = fast_tanh(ht[j * 128 + px]);
        float best = -1e30f; int bi = 0;
        #pragma unroll
        for (int nn = 0; nn < 9; ++nn) {
            float a = w2s[288 + nn];
            #pragma unroll
            for (int i = 0; i < 16; ++i)
                a += h[i] * w2s[nn * 32 + i] + h[16 + i] * w2s[nn * 32 + 16 + i];
            if (a > best) { best = a; bi = nn; }
        }
        bin = bi * 8 + b;
        rank = atomicAdd(&scnt[bin], 1u);
    } else {
        int px = t - 128;
        size_t xo = ((size_t)(px0 + px)) << 6;
        #pragma unroll
        for (int v8 = 0; v8 < 8; ++v8) {
            short8 pk;
            #pragma unroll
            for (int i = 0; i < 8; ++i)
                pk[i] = f2bf(xt[(v8 * 8 + i) * 128 + px]);
            *(short8*)(Xb + xo + v8 * 8) = pk;
        }
    }
    __syncthreads();
    if (t < NBIN && scnt[t]) sbase[t] = atomicAdd(&GC(gcnt, t), scnt[t]);
    __syncthreads();
    if (t < 128) lists[bin * 16384 + sbase[bin] + rank] = (unsigned)(px0 + t);
}

// ---------------------------------------------------------------- K2:
// persistent gathered implicit-GEMM selected conv, REG-STAGED (T14).
// CHUNK=32, 512 blocks (2/CU for stall-hiding), 512 thr (8 waves).
// dbuf 2x36.9 KB. Wave (f=wid&3, gh=wid>>2): ONE 16-px group, 18 MFMA.
// Staging: thread (px = t>>4, part q = t&7, tap-half (t>>3)&1 -> 5/4 taps).
// Local chunk scheduling via LDS prefix + binary search (round 19).
__global__ __launch_bounds__(512, 2) void k_conv(
        const unsigned short* __restrict__ Xb, const unsigned short* __restrict__ WbF,
        const float* __restrict__ kb, const unsigned* __restrict__ lists,
        const unsigned* __restrict__ gcnt,
        unsigned short* __restrict__ Yc, float* __restrict__ sums) {
    __shared__ char blds[2][36864];
    __shared__ unsigned sgc[NBIN];
    __shared__ unsigned sst[NBIN + 1];
    int t = threadIdx.x;
    int wid = t >> 6, lane = t & 63, kg = lane >> 4, l15 = lane & 15;
    int f = wid & 3, gh = wid >> 2;
    int spx = t >> 4, q = t & 7;
    int taphalf = (t >> 3) & 1;
    int tap0 = taphalf * 5;
    int ntap = 5 - taphalf;               // 5 or 4
    int sq8 = (q ^ (spx & 7)) * 8;        // swizzled source part (shorts)
    int sslot = (spx * 8 + q) * 16;       // LDS byte slot within a tap plane

    if (t < NBIN) sgc[t] = GC(gcnt, t);   // 72 parallel loads (one line each)
    __syncthreads();
    if (t == 0) {
        unsigned acc = 0;
        for (int bin = 0; bin < NBIN; ++bin) {
            sst[bin] = acc;
            acc += (sgc[bin] + (CHUNK - 1u)) / CHUNK;
        }
        sst[NBIN] = acc;
    }
    __syncthreads();
    unsigned C = sst[NBIN];

    #define CINFO(K, BIN, CNT, BAS) do {                          \
        int lo_ = 0, hi_ = NBIN;                                  \
        _Pragma("unroll")                                         \
        for (int it_ = 0; it_ < 7; ++it_) {                       \
            if (hi_ - lo_ > 1) {                                  \
                int mid_ = (lo_ + hi_) >> 1;                      \
                if (sst[mid_] <= (K)) lo_ = mid_; else hi_ = mid_;\
            }                                                     \
        }                                                         \
        BIN = lo_;                                                \
        CNT = (int)sgc[lo_];                                      \
        BAS = (int)((K) - sst[lo_]) * CHUNK;                      \
    } while (0)

    unsigned bid = (blockIdx.x & 7) * 64 + (blockIdx.x >> 3);  // XCD-chunked swizzle
    unsigned c0 = (bid * C) / NBLK, c1 = ((bid + 1) * C) / NBLK;
    if (c0 >= c1) return;

    short8 g[5];
    #define GLOAD(P) do {                                                         \
        unsigned p_ = (P);                                                        \
        int h_ = (int)((p_ >> 7) & 127u), w_ = (int)(p_ & 127u);                  \
        unsigned pb_ = p_ & ~16383u;                                              \
        _Pragma("unroll")                                                         \
        for (int k_ = 0; k_ < 5; ++k_) {                                          \
            if (k_ < ntap) {                                                      \
                int tap_ = tap0 + k_;                                             \
                int dh_ = tap_ / 3 - 1, dw_ = tap_ % 3 - 1;                       \
                int h2_ = min(max(h_ + dh_, 0), 127);                             \
                int w2_ = min(max(w_ + dw_, 0), 127);                             \
                g[k_] = *(const short8*)(Xb +                                     \
                    ((size_t)(pb_ | (unsigned)((h2_ << 7) + w2_)) << 6) + sq8);   \
            }                                                                     \
        }                                                                         \
    } while (0)

    #define DSWRITE(BUF) do {                                                     \
        _Pragma("unroll")                                                         \
        for (int k_ = 0; k_ < 5; ++k_)                                            \
            if (k_ < ntap)                                                        \
                *(short8*)(&(BUF)[(tap0 + k_) * 4096 + sslot]) = g[k_];           \
    } while (0)

    // ---- prologue
    int cb, cc_, cbase;
    CINFO(c0, cb, cc_, cbase);
    unsigned cps = lists[cb * 16384 + min(cbase + spx, cc_ - 1)];
    unsigned cpm = lists[cb * 16384 + min(cbase + gh * 16 + l15, cc_ - 1)];
    GLOAD(cps);

    int nb, nc_, nbase;
    {
        unsigned k1 = min(c0 + 1, c1 - 1);
        CINFO(k1, nb, nc_, nbase);
    }
    unsigned nps = lists[nb * 16384 + min(nbase + spx, nc_ - 1)];
    unsigned npm = lists[nb * 16384 + min(nbase + gh * 16 + l15, nc_ - 1)];

    int n = cb >> 3, b = cb & 7;
    short8 wv[18];
    #pragma unroll
    for (int s = 0; s < 18; ++s)
        wv[s] = *(const short8*)(WbF + n * 36864 + ((s * 4 + f) * 64 + lane) * 8);
    f32x4 bias = *(const f32x4*)(kb + n * 64 + f * 16 + kg * 4);

    asm volatile("s_waitcnt vmcnt(0)" ::: "memory");
    DSWRITE(blds[0]);
    asm volatile("s_waitcnt lgkmcnt(0)" ::: "memory");

    int cur = 0;
    float s1[4] = {0.f,0.f,0.f,0.f}, s2[4] = {0.f,0.f,0.f,0.f};

    for (unsigned c = c0; c < c1; ++c) {
        __builtin_amdgcn_s_barrier();      // buf[cur] fully written & prior reads done
        // (1) gathers for chunk c+1 -> regs (deep in flight)
        GLOAD(nps);

        // (2) compute chunk c
        int px = gh * 16 + l15;
        int valid = (cbase + px) < cc_ ? 1 : 0;
        int inb = 0;
        {
            int hh = (int)((cpm >> 7) & 127u), ww = (int)(cpm & 127u);
            #pragma unroll
            for (int tap = 0; tap < 9; ++tap) {
                int dh = tap / 3 - 1, dw = tap % 3 - 1;
                if ((unsigned)(hh + dh) < 128u && (unsigned)(ww + dw) < 128u) inb |= (1 << tap);
            }
            inb = valid ? inb : 0;
        }
        f32x4 acc = (f32x4)0.0f;
        const short8 zero8 = (short8)0;
        const char* bufc = blds[cur];
        #pragma unroll
        for (int s = 0; s < 18; ++s) {
            const int tap = s >> 1;
            const int pr = ((s & 1) << 2) | kg;
            short8 braw = *(const short8*)(bufc + tap * 4096 + px * 128 + ((pr ^ (px & 7)) << 4));
            short8 sel = ((inb >> tap) & 1) ? braw : zero8;
            acc = __builtin_amdgcn_mfma_f32_16x16x32_bf16(
                      __builtin_bit_cast(bf16x8, wv[s]),
                      __builtin_bit_cast(bf16x8, sel), acc, 0, 0, 0);
        }
        // epilogue
        {
            f32x4 o;
            #pragma unroll
            for (int r = 0; r < 4; ++r) o[r] = fmaxf(acc[r] + bias[r], 0.0f);
            if (valid) {
                ushort4v u;
                #pragma unroll
                for (int r = 0; r < 4; ++r) u[r] = (unsigned short)f2bf(o[r]);
                *(ushort4v*)(Yc + (((size_t)cpm) << 6) + f * 16 + kg * 4) = u;
            }
            #pragma unroll
            for (int r = 0; r < 4; ++r) {
                float sv = valid ? o[r] : 0.0f;
                s1[r] += sv;
                s2[r] += sv * sv;
            }
        }

        // (3) meta for chunk c+2 via LDS search (2 lists loads issued LAST)
        int fb, fc2, fbase;
        {
            unsigned k2 = min(c + 2, c1 - 1);
            CINFO(k2, fb, fc2, fbase);
        }
        unsigned fps = lists[fb * 16384 + min(fbase + spx, fc2 - 1)];
        unsigned fpm = lists[fb * 16384 + min(fbase + gh * 16 + l15, fc2 - 1)];

        // (4) gathers landed (2 meta may remain in flight) -> ds_write
        asm volatile("s_waitcnt vmcnt(2)" ::: "memory");
        __builtin_amdgcn_sched_barrier(0);
        DSWRITE(blds[cur ^ 1]);
        asm volatile("s_waitcnt lgkmcnt(0)" ::: "memory");
        __builtin_amdgcn_sched_barrier(0);

        // (5) bin switch: flush stats, reload weights/bias
        if (nb != cb && c + 1 < c1) {
            float f1[4], f2[4];
            #pragma unroll
            for (int r = 0; r < 4; ++r) { f1[r] = s1[r]; f2[r] = s2[r]; s1[r] = 0.f; s2[r] = 0.f; }
            #pragma unroll
            for (int m = 1; m < 16; m <<= 1) {
                #pragma unroll
                for (int r = 0; r < 4; ++r) {
                    f1[r] += __shfl_xor(f1[r], m, 64);
                    f2[r] += __shfl_xor(f2[r], m, 64);
                }
            }
            if (l15 == 0) {
                #pragma unroll
                for (int r = 0; r < 4; ++r) {
                    int ch = f * 16 + kg * 4 + r;
                    atomicAdd(&SM(sums, b * 64 + ch),       f1[r]);
                    atomicAdd(&SM(sums, 512 + b * 64 + ch), f2[r]);
                }
            }
            n = nb >> 3; b = nb & 7;
            #pragma unroll
            for (int s = 0; s < 18; ++s)
                wv[s] = *(const short8*)(WbF + n * 36864 + ((s * 4 + f) * 64 + lane) * 8);
            bias = *(const f32x4*)(kb + n * 64 + f * 16 + kg * 4);
        }

        // rotate pipeline
        cb = nb; cc_ = nc_; cbase = nbase; cpm = npm;
        nb = fb; nc_ = fc2; nbase = fbase; nps = fps; npm = fpm;
        cur ^= 1;
    }

    // final stats flush
    #pragma unroll
    for (int m = 1; m < 16; m <<= 1) {
        #pragma unroll
        for (int r = 0; r < 4; ++r) {
            s1[r] += __shfl_xor(s1[r], m, 64);
            s2[r] += __shfl_xor(s2[r], m, 64);
        }
    }
    if (l15 == 0) {
        #pragma unroll
        for (int r = 0; r < 4; ++r) {
            int ch = f * 16 + kg * 4 + r;
            atomicAdd(&SM(sums, b * 64 + ch),       s1[r]);
            atomicAdd(&SM(sums, 512 + b * 64 + ch), s2[r]);
        }
    }
    #undef GLOAD
    #undef DSWRITE
    #undef CINFO
}

// ---------------------------------------------------------------- K3:
// contiguous bf16 Yc rows -> LDS transpose -> normalized coalesced NCHW f32 store
__global__ void k_final(const unsigned short* __restrict__ Yc, const float* __restrict__ sums,
                        const float* __restrict__ gamma, const float* __restrict__ beta,
                        float* __restrict__ out) {
    __shared__ float ld[128][66];
    __shared__ float smu[64], srs[64], sg[64], sb[64];
    int t = threadIdx.x;
    int b = blockIdx.y, hw0 = blockIdx.x * 128;
    if (t < 64) {
        float mu = SM(sums, b * 64 + t) * (1.0f / HW);
        float vr = SM(sums, 512 + b * 64 + t) * (1.0f / HW) - mu * mu;
        smu[t] = mu;
        srs[t] = rsqrtf(fmaxf(vr, 0.0f) + 1e-5f);
        sg[t] = gamma[t]; sb[t] = beta[t];
    }
    int i = t >> 1, half = t & 1;
    const short8* row = (const short8*)(Yc + (((size_t)(b * HW + hw0 + i)) << 6) + half * 32);
    #pragma unroll
    for (int q = 0; q < 4; ++q) {
        short8 v = row[q];
        #pragma unroll
        for (int j = 0; j < 8; ++j)
            ld[i][half * 32 + q * 8 + j] = bf2f((unsigned short)v[j]);
    }
    __syncthreads();
    #pragma unroll
    for (int rep = 0; rep < 32; ++rep) {
        int idx = rep * 256 + t;          // 8192 = 64c x 128hw
        int c = idx >> 7, j = idx & 127;
        float v = (ld[j][c] - smu[c]) * srs[c] * sg[c] + sb[c];
        out[(((size_t)b * 64 + c) << 14) + hw0 + j] = v;
    }
}

extern "C" void kernel_launch(void* const* d_in, const int* in_sizes, int n_in,
                              void* d_out, int out_size, void* d_ws, size_t ws_size,
                              hipStream_t stream) {
    const float* x    = (const float*)d_in[0];
    const float* kw   = (const float*)d_in[1];
    const float* kb   = (const float*)d_in[2];
    const float* w1   = (const float*)d_in[3];
    const float* b1   = (const float*)d_in[4];
    const float* w2   = (const float*)d_in[5];
    const float* b2   = (const float*)d_in[6];
    const float* gam  = (const float*)d_in[7];
    const float* bet  = (const float*)d_in[8];
    float* out = (float*)d_out;

    char* ws = (char*)d_ws;
    unsigned* gcnt      = (unsigned*)(ws + 0);            // 72 x 64B-padded u32
    float*    sums      = (float*)   (ws + 16384);        // 1024 x 64B-padded f32
    unsigned* lists     = (unsigned*)(ws + 131072);       // 72*16384 u32 (4.72 MB)
    unsigned short* Yc  = (unsigned short*)(ws + 5242880);   // 16.78 MB bf16
    unsigned short* Xb  = (unsigned short*)(ws + 22020096);  // 16.78 MB bf16
    unsigned short* WbF = (unsigned short*)(ws + 38797312);  // 0.66 MB
    // total ws usage ~39.5 MB

    k_zero<<<20, 256, 0, stream>>>((f32x4*)ws);
    k_pre<<<NSCORE + 81, 256, 0, stream>>>(x, w1, b1, w2, b2, kw, gcnt, lists, Xb, WbF);
    k_conv<<<NBLK, 512, 0, stream>>>(Xb, WbF, kb, lists, gcnt, Yc, sums);
    k_final<<<dim3(128, 8), 256, 0, stream>>>(Yc, sums, gam, bet, out);
}

// Round 21
// 79.198 us; speedup vs baseline: 1.2511x; 1.2511x over previous
//
#include <hip/hip_runtime.h>
#include <hip/hip_bf16.h>
#include <stdint.h>

#define B_    8
#define CIN   64
#define COUT  64
#define NPATH 9
#define H_    128
#define W_    128
#define HW    16384
#define PTOT  131072   // B*H*W
#define NBIN  72       // NPATH * B_
#define CHUNK 64       // pixels per chunk
#define NBLK  256      // persistent k_conv blocks (1 per CU)
#define NSCORE 1024    // scoring blocks (128 px each)
#define PMASK 0x1FFFFu // pixel index bits in a list entry (mask in bits 23..31)

typedef float  f32x4   __attribute__((ext_vector_type(4)));
typedef float  f32x16  __attribute__((ext_vector_type(16)));
typedef __bf16 bf16x8  __attribute__((ext_vector_type(8)));
typedef short  short8  __attribute__((ext_vector_type(8)));
typedef unsigned short ushort4v __attribute__((ext_vector_type(4)));

__device__ __forceinline__ short f2bf(float f) {
    __bf16 b = (__bf16)f;
    return __builtin_bit_cast(short, b);
}
__device__ __forceinline__ float bf2f(unsigned short u) {
    unsigned v = ((unsigned)u) << 16;
    return __builtin_bit_cast(float, v);
}
__device__ __forceinline__ float fast_tanh(float a) {
    float e = __builtin_amdgcn_exp2f(a * 2.885390081777927f);
    return 1.0f - 2.0f / (e + 1.0f);
}

// Hot atomic targets padded to one 64B cache line each.
#define GC(arr, i)  ((arr)[(i) * 16])        // gcnt: u32 stride 16
#define SM(arr, i)  ((arr)[(i) * 16])        // sums: f32 stride 16

// ---------------------------------------------------------------- K0:
__global__ void k_zero(f32x4* __restrict__ dst) {
    int i = blockIdx.x * 256 + threadIdx.x;    // 5120 f32x4 = 81920 B
    if (i < 5120) dst[i] = (f32x4)0.0f;
}

// ---------------------------------------------------------------- K1 (fused):
// blocks 0..1023: 128 px/block. x-tile + w1T + w2/b2 in LDS.
//   MLP1 j-stationary; tail: waves 0-1 MLP2/argmax/compaction (list entries
//   carry the 9-tap bounds mask in bits 23..31), waves 2-3 Xb emit.
// blocks 1024..1104: kernels_w -> WbF MFMA-fragment order
__global__ __launch_bounds__(256, 2) void k_pre(
                      const float* __restrict__ x,
                      const float* __restrict__ w1, const float* __restrict__ b1,
                      const float* __restrict__ w2, const float* __restrict__ b2,
                      const float* __restrict__ kw,
                      unsigned* __restrict__ gcnt, unsigned* __restrict__ lists,
                      unsigned short* __restrict__ Xbg,
                      unsigned short* __restrict__ WbF) {
    int t = threadIdx.x;
    if (blockIdx.x >= NSCORE) {
        int ob = ((int)blockIdx.x - NSCORE) * 4096 + t * 16;
        #pragma unroll
        for (int j = 0; j < 16; ++j) {
            int o = ob + j;
            int jj   = o & 7;
            int lane = (o >> 3) & 63;
            int f    = (o >> 9) & 3;
            int rest = o >> 11;
            int s    = rest % 18;
            int n    = rest / 18;
            int c    = f * 16 + (lane & 15);
            int kg   = lane >> 4;
            int ci   = ((s & 1) << 5) + (kg << 3) + jj;
            int tap  = s >> 1;
            WbF[o] = (unsigned short)f2bf(kw[((n * 64 + c) * 64 + ci) * 9 + tap]);
        }
        return;
    }
    __shared__ float xt[64 * 128];     // 32 KB  [ch][px]
    __shared__ float ht[32 * 128];     // 16 KB  [j][px]
    __shared__ float w1t[64 * 36];     // 9.2 KB [ch][j]
    __shared__ float w2s[304];         // 288 w2 + 9 b2
    __shared__ unsigned scnt[NBIN];
    __shared__ unsigned sbase[NBIN];

    int px0 = blockIdx.x * 128;
    int b   = blockIdx.x >> 7;         // 128 blocks per batch
    int hw0 = px0 & 16383;
    if (t < NBIN) scnt[t] = 0u;

    // ---- stage x-tile: 8 coalesced f32x4 per thread
    const float* xbp = x + (((size_t)b) << 20) + hw0;
    #pragma unroll
    for (int i = 0; i < 8; ++i) {
        int flat = i * 256 + t;            // f32x4 id 0..2047
        int ch = flat >> 5, ck = flat & 31;
        f32x4 v = *(const f32x4*)(xbp + ch * HW + ck * 4);
        *(f32x4*)(&xt[ch * 128 + ck * 4]) = v;
    }
    // ---- stage w1 transposed + w2 + b2
    #pragma unroll
    for (int i = 0; i < 8; ++i) {
        int flat = i * 256 + t;            // 0..2047
        int j = flat >> 6, ch = flat & 63;
        w1t[ch * 36 + j] = w1[flat];
    }
    for (int i = t; i < 288; i += 256) w2s[i] = w2[i];
    if (t < 9) w2s[288 + t] = b2[t];
    __syncthreads();

    // ---- MLP1: wave wv owns j in [wv*8, wv*8+8); lane l -> px {2l, 2l+1}
    int wv = t >> 6, l = t & 63;
    {
        float acc[8][2];
        #pragma unroll
        for (int jj = 0; jj < 8; ++jj) {
            float bj = b1[wv * 8 + jj];
            acc[jj][0] = bj; acc[jj][1] = bj;
        }
        #pragma unroll 8
        for (int ch = 0; ch < 64; ++ch) {
            f32x4 wa = *(const f32x4*)(&w1t[ch * 36 + wv * 8]);      // broadcast
            f32x4 wb = *(const f32x4*)(&w1t[ch * 36 + wv * 8 + 4]);  // broadcast
            float2 xx = *(const float2*)(&xt[ch * 128 + l * 2]);
            #pragma unroll
            for (int jj = 0; jj < 4; ++jj) {
                acc[jj][0]     += xx.x * wa[jj];
                acc[jj][1]     += xx.y * wa[jj];
                acc[4 + jj][0] += xx.x * wb[jj];
                acc[4 + jj][1] += xx.y * wb[jj];
            }
        }
        #pragma unroll
        for (int jj = 0; jj < 8; ++jj)
            *(float2*)(&ht[(wv * 8 + jj) * 128 + l * 2]) =
                make_float2(acc[jj][0], acc[jj][1]);
    }
    __syncthreads();

    // ---- tail: waves 0-1 = MLP2/argmax; waves 2-3 = Xb emit
    int bin = 0; unsigned rank = 0, entry = 0;
    if (t < 128) {
        int px = t;
        float h[32];
        #pragma unroll
        for (int j = 0; j < 32; ++j) h[j] = fast_tanh(ht[j * 128 + px]);
        float best = -1e30f; int bi = 0;
        #pragma unroll
        for (int nn = 0; nn < 9; ++nn) {
            float a = w2s[288 + nn];
            #pragma unroll
            for (int i = 0; i < 16; ++i)
                a += h[i] * w2s[nn * 32 + i] + h[16 + i] * w2s[nn * 32 + 16 + i];
            if (a > best) { best = a; bi = nn; }
        }
        bin = bi * 8 + b;
        // 9-tap bounds mask for this pixel
        int p = px0 + px;
        int hh = (p >> 7) & 127, ww = p & 127;
        unsigned m = 0;
        #pragma unroll
        for (int tap = 0; tap < 9; ++tap) {
            int dh = tap / 3 - 1, dw = tap % 3 - 1;
            if ((unsigned)(hh + dh) < 128u && (unsigned)(ww + dw) < 128u) m |= (1u << tap);
        }
        entry = (unsigned)p | (m << 23);
        rank = atomicAdd(&scnt[bin], 1u);
    } else {
        int px = t - 128;
        size_t xo = ((size_t)(px0 + px)) << 6;
        #pragma unroll
        for (int v8 = 0; v8 < 8; ++v8) {
            short8 pk;
            #pragma unroll
            for (int i = 0; i < 8; ++i)
                pk[i] = f2bf(xt[(v8 * 8 + i) * 128 + px]);
            *(short8*)(Xbg + xo + v8 * 8) = pk;
        }
    }
    __syncthreads();
    if (t < NBIN && scnt[t]) sbase[t] = atomicAdd(&GC(gcnt, t), scnt[t]);
    __syncthreads();
    if (t < 128) lists[bin * 16384 + sbase[bin] + rank] = entry;
}

// ---------------------------------------------------------------- K2:
// persistent gathered implicit-GEMM selected conv, REG-STAGED (T14).
// Round-19 config (CHUNK=64, 1 block/CU, dbuf 2x72KB, local LDS scheduling)
// + clamp-free gathers (guard-padded Xbg; OOB taps masked to zero via the
//   precomputed per-pixel mask packed in list entries).
__global__ __launch_bounds__(512, 2) void k_conv(
        const unsigned short* __restrict__ Xbg, const unsigned short* __restrict__ WbF,
        const float* __restrict__ kb, const unsigned* __restrict__ lists,
        const unsigned* __restrict__ gcnt,
        unsigned short* __restrict__ Yc, float* __restrict__ sums) {
    __shared__ char blds[2][73728];
    __shared__ unsigned sgc[NBIN];
    __shared__ unsigned sst[NBIN + 1];
    int t = threadIdx.x;
    int wid = t >> 6, lane = t & 63, kg = lane >> 4, l15 = lane & 15;
    int f = wid & 3, gh = wid >> 2;
    int spx = t >> 3, q = t & 7;
    int sq8 = (q ^ (spx & 7)) * 8;        // swizzled source part (shorts)
    int dst16 = t * 16;                   // linear LDS slot (bytes)

    if (t < NBIN) sgc[t] = GC(gcnt, t);   // 72 parallel loads (one line each)
    __syncthreads();
    if (t == 0) {
        unsigned acc = 0;
        for (int bin = 0; bin < NBIN; ++bin) {
            sst[bin] = acc;
            acc += (sgc[bin] + (CHUNK - 1u)) / CHUNK;
        }
        sst[NBIN] = acc;
    }
    __syncthreads();
    unsigned C = sst[NBIN];

    #define CINFO(K, BIN, CNT, BAS) do {                          \
        int lo_ = 0, hi_ = NBIN;                                  \
        _Pragma("unroll")                                         \
        for (int it_ = 0; it_ < 7; ++it_) {                       \
            if (hi_ - lo_ > 1) {                                  \
                int mid_ = (lo_ + hi_) >> 1;                      \
                if (sst[mid_] <= (K)) lo_ = mid_; else hi_ = mid_;\
            }                                                     \
        }                                                         \
        BIN = lo_;                                                \
        CNT = (int)sgc[lo_];                                      \
        BAS = (int)((K) - sst[lo_]) * CHUNK;                      \
    } while (0)

    unsigned bid = (blockIdx.x & 7) * 32 + (blockIdx.x >> 3);  // XCD-chunked swizzle
    unsigned c0 = (bid * C) / NBLK, c1 = ((bid + 1) * C) / NBLK;
    if (c0 >= c1) return;

    short8 g[9];
    // clamp-free gather: per-tap constant row offset; OOB reads land in the
    // guard region (or a wrong row) and are zeroed later by the entry mask.
    #define GLOAD(E) do {                                                         \
        int pp_ = (int)((E) & PMASK);                                             \
        const unsigned short* bp_ = Xbg + ((size_t)pp_ << 6) + sq8;               \
        g[0] = *(const short8*)(bp_ - 129 * 64);                                  \
        g[1] = *(const short8*)(bp_ - 128 * 64);                                  \
        g[2] = *(const short8*)(bp_ - 127 * 64);                                  \
        g[3] = *(const short8*)(bp_ -   1 * 64);                                  \
        g[4] = *(const short8*)(bp_);                                             \
        g[5] = *(const short8*)(bp_ +   1 * 64);                                  \
        g[6] = *(const short8*)(bp_ + 127 * 64);                                  \
        g[7] = *(const short8*)(bp_ + 128 * 64);                                  \
        g[8] = *(const short8*)(bp_ + 129 * 64);                                  \
    } while (0)

    // ---- prologue
    int cb, cc_, cbase;
    CINFO(c0, cb, cc_, cbase);
    unsigned cps  = lists[cb * 16384 + min(cbase + spx,            cc_ - 1)];
    unsigned cpm0 = lists[cb * 16384 + min(cbase + gh * 32 + l15,      cc_ - 1)];
    unsigned cpm1 = lists[cb * 16384 + min(cbase + gh * 32 + 16 + l15, cc_ - 1)];
    GLOAD(cps);

    int nb, nc_, nbase;
    {
        unsigned k1 = min(c0 + 1, c1 - 1);
        CINFO(k1, nb, nc_, nbase);
    }
    unsigned nps  = lists[nb * 16384 + min(nbase + spx,            nc_ - 1)];
    unsigned npm0 = lists[nb * 16384 + min(nbase + gh * 32 + l15,      nc_ - 1)];
    unsigned npm1 = lists[nb * 16384 + min(nbase + gh * 32 + 16 + l15, nc_ - 1)];

    int n = cb >> 3, b = cb & 7;
    short8 wv[18];
    #pragma unroll
    for (int s = 0; s < 18; ++s)
        wv[s] = *(const short8*)(WbF + n * 36864 + ((s * 4 + f) * 64 + lane) * 8);
    f32x4 bias = *(const f32x4*)(kb + n * 64 + f * 16 + kg * 4);

    asm volatile("s_waitcnt vmcnt(0)" ::: "memory");
    #pragma unroll
    for (int k = 0; k < 9; ++k) *(short8*)(&blds[0][k * 8192 + dst16]) = g[k];
    asm volatile("s_waitcnt lgkmcnt(0)" ::: "memory");

    int cur = 0;
    float s1[4] = {0.f,0.f,0.f,0.f}, s2[4] = {0.f,0.f,0.f,0.f};

    for (unsigned c = c0; c < c1; ++c) {
        __builtin_amdgcn_s_barrier();      // buf[cur] fully written & prior reads done
        // (1) gathers for chunk c+1 -> regs (deep in flight)
        GLOAD(nps);

        // (2) compute chunk c (masks come packed in the entries)
        int v0 = (cbase + gh * 32 + l15)      < cc_ ? 1 : 0;
        int v1 = (cbase + gh * 32 + 16 + l15) < cc_ ? 1 : 0;
        int inb0 = v0 ? (int)(cpm0 >> 23) : 0;
        int inb1 = v1 ? (int)(cpm1 >> 23) : 0;
        f32x4 acc0 = (f32x4)0.0f, acc1 = (f32x4)0.0f;
        const short8 zero8 = (short8)0;
        const char* bufc = blds[cur];
        int pxa = gh * 32 + l15, pxb = pxa + 16;
        #pragma unroll
        for (int s = 0; s < 18; ++s) {
            const int tap = s >> 1;
            const int pr = ((s & 1) << 2) | kg;
            bf16x8 af = __builtin_bit_cast(bf16x8, wv[s]);
            short8 ra = *(const short8*)(bufc + tap * 8192 + pxa * 128 + ((pr ^ (pxa & 7)) << 4));
            short8 rb = *(const short8*)(bufc + tap * 8192 + pxb * 128 + ((pr ^ (pxb & 7)) << 4));
            short8 sa = ((inb0 >> tap) & 1) ? ra : zero8;
            short8 sb = ((inb1 >> tap) & 1) ? rb : zero8;
            acc0 = __builtin_amdgcn_mfma_f32_16x16x32_bf16(af, __builtin_bit_cast(bf16x8, sa), acc0, 0, 0, 0);
            acc1 = __builtin_amdgcn_mfma_f32_16x16x32_bf16(af, __builtin_bit_cast(bf16x8, sb), acc1, 0, 0, 0);
        }
        // epilogue
        {
            f32x4 o0, o1;
            #pragma unroll
            for (int r = 0; r < 4; ++r) {
                o0[r] = fmaxf(acc0[r] + bias[r], 0.0f);
                o1[r] = fmaxf(acc1[r] + bias[r], 0.0f);
            }
            if (v0) {
                ushort4v u;
                #pragma unroll
                for (int r = 0; r < 4; ++r) u[r] = (unsigned short)f2bf(o0[r]);
                *(ushort4v*)(Yc + (((size_t)(cpm0 & PMASK)) << 6) + f * 16 + kg * 4) = u;
            }
            if (v1) {
                ushort4v u;
                #pragma unroll
                for (int r = 0; r < 4; ++r) u[r] = (unsigned short)f2bf(o1[r]);
                *(ushort4v*)(Yc + (((size_t)(cpm1 & PMASK)) << 6) + f * 16 + kg * 4) = u;
            }
            #pragma unroll
            for (int r = 0; r < 4; ++r) {
                float a = v0 ? o0[r] : 0.0f, bb = v1 ? o1[r] : 0.0f;
                s1[r] += a + bb;
                s2[r] += a * a + bb * bb;
            }
        }

        // (3) meta for chunk c+2 via LDS search (3 lists loads issued LAST)
        int fb, fc2, fbase;
        {
            unsigned k2 = min(c + 2, c1 - 1);
            CINFO(k2, fb, fc2, fbase);
        }
        unsigned fps  = lists[fb * 16384 + min(fbase + spx,            fc2 - 1)];
        unsigned fpm0 = lists[fb * 16384 + min(fbase + gh * 32 + l15,      fc2 - 1)];
        unsigned fpm1 = lists[fb * 16384 + min(fbase + gh * 32 + 16 + l15, fc2 - 1)];

        // (4) gathers landed -> ds_write
        asm volatile("s_waitcnt vmcnt(3)" ::: "memory");
        __builtin_amdgcn_sched_barrier(0);
        #pragma unroll
        for (int k = 0; k < 9; ++k) *(short8*)(&blds[cur ^ 1][k * 8192 + dst16]) = g[k];
        asm volatile("s_waitcnt lgkmcnt(0)" ::: "memory");
        __builtin_amdgcn_sched_barrier(0);

        // (5) bin switch: flush stats, reload weights/bias
        if (nb != cb && c + 1 < c1) {
            float f1[4], f2[4];
            #pragma unroll
            for (int r = 0; r < 4; ++r) { f1[r] = s1[r]; f2[r] = s2[r]; s1[r] = 0.f; s2[r] = 0.f; }
            #pragma unroll
            for (int m = 1; m < 16; m <<= 1) {
                #pragma unroll
                for (int r = 0; r < 4; ++r) {
                    f1[r] += __shfl_xor(f1[r], m, 64);
                    f2[r] += __shfl_xor(f2[r], m, 64);
                }
            }
            if (l15 == 0) {
                #pragma unroll
                for (int r = 0; r < 4; ++r) {
                    int ch = f * 16 + kg * 4 + r;
                    atomicAdd(&SM(sums, b * 64 + ch),       f1[r]);
                    atomicAdd(&SM(sums, 512 + b * 64 + ch), f2[r]);
                }
            }
            n = nb >> 3; b = nb & 7;
            #pragma unroll
            for (int s = 0; s < 18; ++s)
                wv[s] = *(const short8*)(WbF + n * 36864 + ((s * 4 + f) * 64 + lane) * 8);
            bias = *(const f32x4*)(kb + n * 64 + f * 16 + kg * 4);
        }

        // rotate pipeline
        cb = nb; cc_ = nc_; cbase = nbase; cpm0 = npm0; cpm1 = npm1;
        nb = fb; nc_ = fc2; nbase = fbase; nps = fps; npm0 = fpm0; npm1 = fpm1;
        cur ^= 1;
    }

    // final stats flush
    #pragma unroll
    for (int m = 1; m < 16; m <<= 1) {
        #pragma unroll
        for (int r = 0; r < 4; ++r) {
            s1[r] += __shfl_xor(s1[r], m, 64);
            s2[r] += __shfl_xor(s2[r], m, 64);
        }
    }
    if (l15 == 0) {
        #pragma unroll
        for (int r = 0; r < 4; ++r) {
            int ch = f * 16 + kg * 4 + r;
            atomicAdd(&SM(sums, b * 64 + ch),       s1[r]);
            atomicAdd(&SM(sums, 512 + b * 64 + ch), s2[r]);
        }
    }
    #undef GLOAD
    #undef CINFO
}

// ---------------------------------------------------------------- K3:
// contiguous bf16 Yc rows -> LDS transpose -> normalized coalesced NCHW f32 store
__global__ void k_final(const unsigned short* __restrict__ Yc, const float* __restrict__ sums,
                        const float* __restrict__ gamma, const float* __restrict__ beta,
                        float* __restrict__ out) {
    __shared__ float ld[128][66];
    __shared__ float smu[64], srs[64], sg[64], sb[64];
    int t = threadIdx.x;
    int b = blockIdx.y, hw0 = blockIdx.x * 128;
    if (t < 64) {
        float mu = SM(sums, b * 64 + t) * (1.0f / HW);
        float vr = SM(sums, 512 + b * 64 + t) * (1.0f / HW) - mu * mu;
        smu[t] = mu;
        srs[t] = rsqrtf(fmaxf(vr, 0.0f) + 1e-5f);
        sg[t] = gamma[t]; sb[t] = beta[t];
    }
    int i = t >> 1, half = t & 1;
    const short8* row = (const short8*)(Yc + (((size_t)(b * HW + hw0 + i)) << 6) + half * 32);
    #pragma unroll
    for (int q = 0; q < 4; ++q) {
        short8 v = row[q];
        #pragma unroll
        for (int j = 0; j < 8; ++j)
            ld[i][half * 32 + q * 8 + j] = bf2f((unsigned short)v[j]);
    }
    __syncthreads();
    #pragma unroll
    for (int rep = 0; rep < 32; ++rep) {
        int idx = rep * 256 + t;          // 8192 = 64c x 128hw
        int c = idx >> 7, j = idx & 127;
        float v = (ld[j][c] - smu[c]) * srs[c] * sg[c] + sb[c];
        out[(((size_t)b * 64 + c) << 14) + hw0 + j] = v;
    }
}

extern "C" void kernel_launch(void* const* d_in, const int* in_sizes, int n_in,
                              void* d_out, int out_size, void* d_ws, size_t ws_size,
                              hipStream_t stream) {
    const float* x    = (const float*)d_in[0];
    const float* kw   = (const float*)d_in[1];
    const float* kb   = (const float*)d_in[2];
    const float* w1   = (const float*)d_in[3];
    const float* b1   = (const float*)d_in[4];
    const float* w2   = (const float*)d_in[5];
    const float* b2   = (const float*)d_in[6];
    const float* gam  = (const float*)d_in[7];
    const float* bet  = (const float*)d_in[8];
    float* out = (float*)d_out;

    char* ws = (char*)d_ws;
    unsigned* gcnt      = (unsigned*)(ws + 0);            // 72 x 64B-padded u32
    float*    sums      = (float*)   (ws + 16384);        // 1024 x 64B-padded f32
    unsigned* lists     = (unsigned*)(ws + 131072);       // 72*16384 u32 (4.72 MB)
    unsigned short* Yc  = (unsigned short*)(ws + 5242880);   // 16.78 MB bf16
    // Xb with 129-row (16512 B) guard on each side for clamp-free gathers
    unsigned short* Xbg = (unsigned short*)(ws + 22020096) + 8256;
    unsigned short* WbF = (unsigned short*)(ws + 38862848);  // 0.66 MB
    // total ws usage ~39.6 MB

    k_zero<<<20, 256, 0, stream>>>((f32x4*)ws);
    k_pre<<<NSCORE + 81, 256, 0, stream>>>(x, w1, b1, w2, b2, kw, gcnt, lists, Xbg, WbF);
    k_conv<<<NBLK, 512, 0, stream>>>(Xbg, WbF, kb, lists, gcnt, Yc, sums);
    k_final<<<dim3(128, 8), 256, 0, stream>>>(Yc, sums, gam, bet, out);
}